// Round 1
// baseline (337.193 us; speedup 1.0000x reference)
//
#include <hip/hip_runtime.h>
#include <hip/hip_bf16.h>
#include <math.h>

#define B_    4
#define N_    2048
#define INF_  256
#define OUTF_ 64
#define H_    8
#define C_    512   // H_*OUTF_ (output feature dim)

// ---------------------------------------------------------------------------
// Kernel 1: projection GEMM  h[8192,512] = x[8192,256] @ W[256,512]   (fp32)
// BM=128, BN=128, BK=16, 256 threads, 8x8 per thread
// ---------------------------------------------------------------------------
__global__ __launch_bounds__(256)
void proj_gemm(const float* __restrict__ x, const float* __restrict__ w,
               float* __restrict__ h) {
    const int BM = 128, BN = 128, BK = 16;
    __shared__ float As[BK][BM];
    __shared__ float Bs[BK][BN];
    const int tid = threadIdx.x;
    const int m0 = blockIdx.x * BM;
    const int n0 = blockIdx.y * BN;
    const int tr = tid >> 4;   // 0..15
    const int tc = tid & 15;   // 0..15
    float acc[8][8] = {};
    for (int k0 = 0; k0 < INF_; k0 += BK) {
        // A tile: 128 rows x 16 k. 512 float4, 2 per thread. Store transposed As[k][m].
#pragma unroll
        for (int l = 0; l < 2; ++l) {
            int idx = tid + l * 256;
            int row = idx >> 2;
            int k4  = (idx & 3) * 4;
            const float4 v = *reinterpret_cast<const float4*>(&x[(size_t)(m0 + row) * INF_ + k0 + k4]);
            As[k4 + 0][row] = v.x; As[k4 + 1][row] = v.y;
            As[k4 + 2][row] = v.z; As[k4 + 3][row] = v.w;
        }
        // B tile: 16 rows x 128 cols. natural layout.
#pragma unroll
        for (int l = 0; l < 2; ++l) {
            int idx = tid + l * 256;
            int kk = idx >> 5;
            int c4 = (idx & 31) * 4;
            *reinterpret_cast<float4*>(&Bs[kk][c4]) =
                *reinterpret_cast<const float4*>(&w[(size_t)(k0 + kk) * C_ + n0 + c4]);
        }
        __syncthreads();
#pragma unroll
        for (int k = 0; k < BK; ++k) {
            float a[8], b[8];
            *(float4*)&a[0] = *(const float4*)&As[k][tr * 8];
            *(float4*)&a[4] = *(const float4*)&As[k][tr * 8 + 4];
            *(float4*)&b[0] = *(const float4*)&Bs[k][tc * 8];
            *(float4*)&b[4] = *(const float4*)&Bs[k][tc * 8 + 4];
#pragma unroll
            for (int i = 0; i < 8; ++i)
#pragma unroll
                for (int j = 0; j < 8; ++j)
                    acc[i][j] = fmaf(a[i], b[j], acc[i][j]);
        }
        __syncthreads();
    }
#pragma unroll
    for (int i = 0; i < 8; ++i) {
#pragma unroll
        for (int j = 0; j < 8; j += 4) {
            float4 v = { acc[i][j], acc[i][j + 1], acc[i][j + 2], acc[i][j + 3] };
            *reinterpret_cast<float4*>(&h[(size_t)(m0 + tr * 8 + i) * C_ + n0 + tc * 8 + j]) = v;
        }
    }
}

// ---------------------------------------------------------------------------
// Kernel 2: e[row,h] = exp( sum_f h[row, h*64+f] * attn_dst[h,f] )
// one wave per row (8192 rows); block = 256 threads = 4 waves
// ---------------------------------------------------------------------------
__global__ __launch_bounds__(256)
void e_kernel(const float* __restrict__ h, const float* __restrict__ attn_dst,
              float* __restrict__ e) {
    int row  = blockIdx.x * 4 + (threadIdx.x >> 6);
    int lane = threadIdx.x & 63;
    if (row >= B_ * N_) return;
    const float* hr = h + (size_t)row * C_;
    float4 hv0 = *reinterpret_cast<const float4*>(&hr[lane * 8]);
    float4 hv1 = *reinterpret_cast<const float4*>(&hr[lane * 8 + 4]);
    float4 av0 = *reinterpret_cast<const float4*>(&attn_dst[lane * 8]);
    float4 av1 = *reinterpret_cast<const float4*>(&attn_dst[lane * 8 + 4]);
    float s = hv0.x * av0.x + hv0.y * av0.y + hv0.z * av0.z + hv0.w * av0.w
            + hv1.x * av1.x + hv1.y * av1.y + hv1.z * av1.z + hv1.w * av1.w;
    s += __shfl_xor(s, 1);
    s += __shfl_xor(s, 2);
    s += __shfl_xor(s, 4);
    if ((lane & 7) == 0) e[(size_t)row * 8 + (lane >> 3)] = expf(s);
}

// ---------------------------------------------------------------------------
// Kernel 3: den[b,i,h] = sum_j adj[b,i,j] * e[b,j,h]
// one block (256 threads) per output row (b,i)
// ---------------------------------------------------------------------------
__global__ __launch_bounds__(256)
void den_kernel(const int* __restrict__ adj, const float* __restrict__ e,
                float* __restrict__ den) {
    int bi = blockIdx.x;                 // 0..8191  (= b*2048 + i)
    int b  = bi >> 11;
    const int*   arow = adj + (size_t)bi * N_;
    const float* eb   = e + (size_t)b * N_ * 8;
    float acc[8] = {};
    for (int j = threadIdx.x; j < N_; j += 256) {
        if (arow[j]) {
            const float4 e0 = *reinterpret_cast<const float4*>(&eb[j * 8]);
            const float4 e1 = *reinterpret_cast<const float4*>(&eb[j * 8 + 4]);
            acc[0] += e0.x; acc[1] += e0.y; acc[2] += e0.z; acc[3] += e0.w;
            acc[4] += e1.x; acc[5] += e1.y; acc[6] += e1.z; acc[7] += e1.w;
        }
    }
#pragma unroll
    for (int off = 1; off < 64; off <<= 1)
#pragma unroll
        for (int hh = 0; hh < 8; ++hh) acc[hh] += __shfl_xor(acc[hh], off);
    __shared__ float red[4][8];
    int lane = threadIdx.x & 63, wv = threadIdx.x >> 6;
    if (lane == 0)
#pragma unroll
        for (int hh = 0; hh < 8; ++hh) red[wv][hh] = acc[hh];
    __syncthreads();
    if (threadIdx.x < 8) {
        float s = red[0][threadIdx.x] + red[1][threadIdx.x]
                + red[2][threadIdx.x] + red[3][threadIdx.x];
        den[(size_t)bi * 8 + threadIdx.x] = s;
    }
}

// ---------------------------------------------------------------------------
// Kernel 4: numerator GEMM per batch:
//   num[i, c] = sum_j adj[b,i,j] * ( e[b,j,c>>6] * h[b,j,c] )
// BM=128, BN=128, BK=16, 256 threads, 8x8 per thread. Writes num to out.
// ---------------------------------------------------------------------------
__global__ __launch_bounds__(256)
void agg_gemm(const int* __restrict__ adj, const float* __restrict__ h,
              const float* __restrict__ e, float* __restrict__ out) {
    const int BM = 128, BN = 128, BK = 16;
    __shared__ float As[BK][BM];
    __shared__ float Bs[BK][BN];
    const int b  = blockIdx.z;
    const int m0 = blockIdx.x * BM;
    const int n0 = blockIdx.y * BN;
    const int tid = threadIdx.x;
    const int tr = tid >> 4, tc = tid & 15;
    const int*   A  = adj + (size_t)b * N_ * N_;
    const float* hb = h + (size_t)b * N_ * C_;
    const float* eb = e + (size_t)b * N_ * 8;
    float acc[8][8] = {};
    for (int k0 = 0; k0 < N_; k0 += BK) {
        // A tile (adj, int -> float), transposed store As[k][m]
#pragma unroll
        for (int l = 0; l < 2; ++l) {
            int idx = tid + l * 256;
            int row = idx >> 2;
            int k4  = (idx & 3) * 4;
            const int4 v = *reinterpret_cast<const int4*>(&A[(size_t)(m0 + row) * N_ + k0 + k4]);
            As[k4 + 0][row] = (float)v.x; As[k4 + 1][row] = (float)v.y;
            As[k4 + 2][row] = (float)v.z; As[k4 + 3][row] = (float)v.w;
        }
        // B tile: g[k, c] = e[k, head] * h[k, c]
#pragma unroll
        for (int l = 0; l < 2; ++l) {
            int idx = tid + l * 256;
            int kk = idx >> 5;
            int c4 = (idx & 31) * 4;
            int gc = n0 + c4;
            float ev = eb[(size_t)(k0 + kk) * 8 + (gc >> 6)];
            float4 v = *reinterpret_cast<const float4*>(&hb[(size_t)(k0 + kk) * C_ + gc]);
            v.x *= ev; v.y *= ev; v.z *= ev; v.w *= ev;
            *reinterpret_cast<float4*>(&Bs[kk][c4]) = v;
        }
        __syncthreads();
#pragma unroll
        for (int k = 0; k < BK; ++k) {
            float a[8], bb[8];
            *(float4*)&a[0]  = *(const float4*)&As[k][tr * 8];
            *(float4*)&a[4]  = *(const float4*)&As[k][tr * 8 + 4];
            *(float4*)&bb[0] = *(const float4*)&Bs[k][tc * 8];
            *(float4*)&bb[4] = *(const float4*)&Bs[k][tc * 8 + 4];
#pragma unroll
            for (int i = 0; i < 8; ++i)
#pragma unroll
                for (int j = 0; j < 8; ++j)
                    acc[i][j] = fmaf(a[i], bb[j], acc[i][j]);
        }
        __syncthreads();
    }
#pragma unroll
    for (int i = 0; i < 8; ++i) {
#pragma unroll
        for (int j = 0; j < 8; j += 4) {
            float4 v = { acc[i][j], acc[i][j + 1], acc[i][j + 2], acc[i][j + 3] };
            *reinterpret_cast<float4*>(
                &out[((size_t)b * N_ + m0 + tr * 8 + i) * C_ + n0 + tc * 8 + j]) = v;
        }
    }
}

// ---------------------------------------------------------------------------
// Kernel 5: out /= den (broadcast per 64-col head group)
// ---------------------------------------------------------------------------
__global__ __launch_bounds__(256)
void div_kernel(float* __restrict__ out, const float* __restrict__ den) {
    size_t idx = (size_t)blockIdx.x * 256 + threadIdx.x;   // float4 index
    const size_t total4 = (size_t)B_ * N_ * C_ / 4;
    if (idx >= total4) return;
    size_t c0  = idx * 4;
    size_t row = c0 / C_;
    int    col = (int)(c0 % C_);
    float inv = 1.0f / den[row * 8 + (col >> 6)];
    float4 v = reinterpret_cast<float4*>(out)[idx];
    v.x *= inv; v.y *= inv; v.z *= inv; v.w *= inv;
    reinterpret_cast<float4*>(out)[idx] = v;
}

// ---------------------------------------------------------------------------
extern "C" void kernel_launch(void* const* d_in, const int* in_sizes, int n_in,
                              void* d_out, int out_size, void* d_ws, size_t ws_size,
                              hipStream_t stream) {
    const float* x        = (const float*)d_in[0];
    const int*   adj      = (const int*)d_in[1];
    const float* weight   = (const float*)d_in[2];
    // d_in[3] = attn_src : unused (cancels in softmax over j)
    const float* attn_dst = (const float*)d_in[4];
    float* out = (float*)d_out;

    // workspace layout (floats):
    //   h   : B*N*C_            = 4,194,304 floats (16 MiB)
    //   e   : B*N*8             =    65,536 floats (256 KiB)
    //   den : B*N*8             =    65,536 floats (256 KiB)
    float* h   = (float*)d_ws;
    float* e   = h + (size_t)B_ * N_ * C_;
    float* den = e + (size_t)B_ * N_ * 8;

    // 1. projection
    {
        dim3 grid((B_ * N_) / 128, C_ / 128);
        proj_gemm<<<grid, 256, 0, stream>>>(x, weight, h);
    }
    // 2. e = exp(dst)
    {
        dim3 grid((B_ * N_) / 4);
        e_kernel<<<grid, 256, 0, stream>>>(h, attn_dst, e);
    }
    // 3. denominator
    {
        dim3 grid(B_ * N_);
        den_kernel<<<grid, 256, 0, stream>>>(adj, e, den);
    }
    // 4. numerator GEMM -> out
    {
        dim3 grid(N_ / 128, C_ / 128, B_);
        agg_gemm<<<grid, 256, 0, stream>>>(adj, h, e, out);
    }
    // 5. divide
    {
        size_t total4 = (size_t)B_ * N_ * C_ / 4;
        dim3 grid((unsigned)((total4 + 255) / 256));
        div_kernel<<<grid, 256, 0, stream>>>(out, den);
    }
}

// Round 2
// 127.766 us; speedup vs baseline: 2.6391x; 2.6391x over previous
//
#include <hip/hip_runtime.h>
#include <hip/hip_bf16.h>
#include <math.h>

#define B_    4
#define N_    2048
#define INF_  256
#define OUTF_ 64
#define H_    8
#define C_    512   // H_*OUTF_

typedef __attribute__((ext_vector_type(8))) short  bf16x8;
typedef __attribute__((ext_vector_type(4))) float  f32x4;

static __device__ __forceinline__ short f2b(float f) {
    union { float f; unsigned u; } v; v.f = f;
    unsigned r = (v.u + 0x7FFFu + ((v.u >> 16) & 1u)) >> 16;  // RNE
    return (short)r;
}
static __device__ __forceinline__ float b2f(short s) {
    union { unsigned u; float f; } v; v.u = ((unsigned)(unsigned short)s) << 16;
    return v.f;
}

#define GL2LDS(gsrc, ldst)                                                          \
    __builtin_amdgcn_global_load_lds(                                               \
        (const __attribute__((address_space(1))) void*)(gsrc),                      \
        (__attribute__((address_space(3))) void*)(ldst), 16, 0, 0)

// ---------------------------------------------------------------------------
// Kernel 1: projection GEMM  h[8192,512] = x[8192,256] @ W[256,512]   (fp32)
// ---------------------------------------------------------------------------
__global__ __launch_bounds__(256)
void proj_gemm(const float* __restrict__ x, const float* __restrict__ w,
               float* __restrict__ h) {
    const int BMp = 128, BNp = 128, BKp = 16;
    __shared__ float As[BKp][BMp];
    __shared__ float Bs[BKp][BNp];
    const int tid = threadIdx.x;
    const int m0 = blockIdx.x * BMp;
    const int n0 = blockIdx.y * BNp;
    const int tr = tid >> 4;
    const int tc = tid & 15;
    float acc[8][8] = {};
    for (int k0 = 0; k0 < INF_; k0 += BKp) {
#pragma unroll
        for (int l = 0; l < 2; ++l) {
            int idx = tid + l * 256;
            int row = idx >> 2;
            int k4  = (idx & 3) * 4;
            const float4 v = *reinterpret_cast<const float4*>(&x[(size_t)(m0 + row) * INF_ + k0 + k4]);
            As[k4 + 0][row] = v.x; As[k4 + 1][row] = v.y;
            As[k4 + 2][row] = v.z; As[k4 + 3][row] = v.w;
        }
#pragma unroll
        for (int l = 0; l < 2; ++l) {
            int idx = tid + l * 256;
            int kk = idx >> 5;
            int c4 = (idx & 31) * 4;
            *reinterpret_cast<float4*>(&Bs[kk][c4]) =
                *reinterpret_cast<const float4*>(&w[(size_t)(k0 + kk) * C_ + n0 + c4]);
        }
        __syncthreads();
#pragma unroll
        for (int k = 0; k < BKp; ++k) {
            float a[8], b[8];
            *(float4*)&a[0] = *(const float4*)&As[k][tr * 8];
            *(float4*)&a[4] = *(const float4*)&As[k][tr * 8 + 4];
            *(float4*)&b[0] = *(const float4*)&Bs[k][tc * 8];
            *(float4*)&b[4] = *(const float4*)&Bs[k][tc * 8 + 4];
#pragma unroll
            for (int i = 0; i < 8; ++i)
#pragma unroll
                for (int j = 0; j < 8; ++j)
                    acc[i][j] = fmaf(a[i], b[j], acc[i][j]);
        }
        __syncthreads();
    }
#pragma unroll
    for (int i = 0; i < 8; ++i) {
#pragma unroll
        for (int j = 0; j < 8; j += 4) {
            float4 v = { acc[i][j], acc[i][j + 1], acc[i][j + 2], acc[i][j + 3] };
            *reinterpret_cast<float4*>(&h[(size_t)(m0 + tr * 8 + i) * C_ + n0 + tc * 8 + j]) = v;
        }
    }
}

// ---------------------------------------------------------------------------
// Kernel 2: eT[b][h][j] = exp(h[b,j,h*64:].dot(attn_dst[h]))  (fp32 + bf16)
// one wave per row
// ---------------------------------------------------------------------------
__global__ __launch_bounds__(256)
void e_kernel(const float* __restrict__ h, const float* __restrict__ attn_dst,
              float* __restrict__ eT, short* __restrict__ eTb) {
    int row  = blockIdx.x * 4 + (threadIdx.x >> 6);
    int lane = threadIdx.x & 63;
    const float* hr = h + (size_t)row * C_;
    float4 hv0 = *reinterpret_cast<const float4*>(&hr[lane * 8]);
    float4 hv1 = *reinterpret_cast<const float4*>(&hr[lane * 8 + 4]);
    float4 av0 = *reinterpret_cast<const float4*>(&attn_dst[lane * 8]);
    float4 av1 = *reinterpret_cast<const float4*>(&attn_dst[lane * 8 + 4]);
    float s = hv0.x * av0.x + hv0.y * av0.y + hv0.z * av0.z + hv0.w * av0.w
            + hv1.x * av1.x + hv1.y * av1.y + hv1.z * av1.z + hv1.w * av1.w;
    s += __shfl_xor(s, 1);
    s += __shfl_xor(s, 2);
    s += __shfl_xor(s, 4);
    if ((lane & 7) == 0) {
        int b = row >> 11, j = row & (N_ - 1), hh = lane >> 3;
        float ev = expf(s);
        size_t o = ((size_t)b * H_ + hh) * N_ + j;
        eT[o]  = ev;
        eTb[o] = f2b(ev);
    }
}

// ---------------------------------------------------------------------------
// Kernel 3: adjb = bf16(adj)  (elementwise, 8 per thread)
// ---------------------------------------------------------------------------
__global__ __launch_bounds__(256)
void adjb_kernel(const int* __restrict__ adj, short* __restrict__ adjb) {
    size_t i8 = (size_t)blockIdx.x * 256 + threadIdx.x;
    const int4* p = reinterpret_cast<const int4*>(adj + i8 * 8);
    int4 v0 = p[0], v1 = p[1];
    bf16x8 o;
    o[0] = v0.x ? (short)0x3F80 : (short)0;
    o[1] = v0.y ? (short)0x3F80 : (short)0;
    o[2] = v0.z ? (short)0x3F80 : (short)0;
    o[3] = v0.w ? (short)0x3F80 : (short)0;
    o[4] = v1.x ? (short)0x3F80 : (short)0;
    o[5] = v1.y ? (short)0x3F80 : (short)0;
    o[6] = v1.z ? (short)0x3F80 : (short)0;
    o[7] = v1.w ? (short)0x3F80 : (short)0;
    *reinterpret_cast<bf16x8*>(adjb + i8 * 8) = o;
}

// ---------------------------------------------------------------------------
// Kernel 4: gT[b][c][j] = bf16(eT[b][c>>6][j] * h[b,j,c])  via LDS transpose
// block: 64(j) x 64(c) tile
// ---------------------------------------------------------------------------
__global__ __launch_bounds__(256)
void gT_kernel(const float* __restrict__ h, const float* __restrict__ eT,
               short* __restrict__ gT) {
    __shared__ short T[64][72];   // [c][j], padded
    const int b  = blockIdx.z;
    const int j0 = blockIdx.x * 64;
    const int c0 = blockIdx.y * 64;
    const int head = c0 >> 6;
    const int t = threadIdx.x;
    const int cl = (t & 15) * 4;
#pragma unroll
    for (int p = 0; p < 4; ++p) {
        int jl = p * 16 + (t >> 4);
        float ev = eT[((size_t)b * H_ + head) * N_ + j0 + jl];
        float4 v = *reinterpret_cast<const float4*>(&h[((size_t)b * N_ + j0 + jl) * C_ + c0 + cl]);
        T[cl + 0][jl] = f2b(v.x * ev);
        T[cl + 1][jl] = f2b(v.y * ev);
        T[cl + 2][jl] = f2b(v.z * ev);
        T[cl + 3][jl] = f2b(v.w * ev);
    }
    __syncthreads();
    const int cr = t >> 2;
    const int js = (t & 3) * 16;
    bf16x8 w0 = *reinterpret_cast<const bf16x8*>(&T[cr][js]);
    bf16x8 w1 = *reinterpret_cast<const bf16x8*>(&T[cr][js + 8]);
    short* dst = &gT[((size_t)b * C_ + c0 + cr) * N_ + j0 + js];
    *reinterpret_cast<bf16x8*>(dst)     = w0;
    *reinterpret_cast<bf16x8*>(dst + 8) = w1;
}

// ---------------------------------------------------------------------------
// Kernel 5: den[b,i,h] = sum_j adjb[b,i,j] * eTb[b,h,j]
// block per row (b,i); eTb batch staged in LDS (32KB)
// ---------------------------------------------------------------------------
__global__ __launch_bounds__(256)
void den_kernel(const short* __restrict__ adjb, const short* __restrict__ eTb,
                float* __restrict__ den) {
    __shared__ short E[H_ * N_];       // 32 KiB
    __shared__ float red[4][8];
    const int bi = blockIdx.x;
    const int b  = bi >> 11;
    const short* esrc = eTb + (size_t)b * H_ * N_;
#pragma unroll
    for (int q = 0; q < 8; ++q) {
        int o = (q * 256 + threadIdx.x) * 8;
        *reinterpret_cast<bf16x8*>(&E[o]) = *reinterpret_cast<const bf16x8*>(&esrc[o]);
    }
    __syncthreads();
    const short* arow = adjb + (size_t)bi * N_;
    const int j0 = threadIdx.x * 8;
    bf16x8 av = *reinterpret_cast<const bf16x8*>(&arow[j0]);
    float a_f[8];
#pragma unroll
    for (int u = 0; u < 8; ++u) a_f[u] = b2f(av[u]);
    float acc[8];
#pragma unroll
    for (int hh = 0; hh < 8; ++hh) {
        bf16x8 ev = *reinterpret_cast<const bf16x8*>(&E[hh * N_ + j0]);
        float s = 0.f;
#pragma unroll
        for (int u = 0; u < 8; ++u) s = fmaf(a_f[u], b2f(ev[u]), s);
        acc[hh] = s;
    }
#pragma unroll
    for (int off = 1; off < 64; off <<= 1)
#pragma unroll
        for (int hh = 0; hh < 8; ++hh) acc[hh] += __shfl_xor(acc[hh], off);
    int lane = threadIdx.x & 63, wv = threadIdx.x >> 6;
    if (lane == 0)
#pragma unroll
        for (int hh = 0; hh < 8; ++hh) red[wv][hh] = acc[hh];
    __syncthreads();
    if (threadIdx.x < 8) {
        float s = red[0][threadIdx.x] + red[1][threadIdx.x]
                + red[2][threadIdx.x] + red[3][threadIdx.x];
        den[(size_t)bi * 8 + threadIdx.x] = s;
    }
}

// ---------------------------------------------------------------------------
// Kernel 6: numerator GEMM (bf16 MFMA):
//   out[b,i,c] = sum_j adjb[b,i,j] * gT[b,c,j]
// BM=128, BN=64, BK=64; 256 threads = 4 waves (2x2), wave tile 64x32.
// global_load_lds staging, XOR-swizzled LDS (elem ^= (row&7)*8).
// ---------------------------------------------------------------------------
__global__ __launch_bounds__(256)
void agg_mfma(const short* __restrict__ adjb, const short* __restrict__ gT,
              float* __restrict__ out) {
    __shared__ short As[128 * 64];   // 16 KiB  [row i 0..127][k 0..63]
    __shared__ short Bs[64 * 64];    //  8 KiB  [row c 0..63 ][k 0..63]
    const int b  = blockIdx.z;
    const int m0 = blockIdx.x * 128;
    const int n0 = blockIdx.y * 64;
    const int wid  = threadIdx.x >> 6;
    const int lane = threadIdx.x & 63;
    const int wr = wid >> 1, wc = wid & 1;
    const int lr = lane >> 3;               // 0..7 : row-within-8 for staging
    const int ls = (lane & 7) ^ lr;         // swizzled 16B slot (0..7)
    const short* Abase = adjb + (size_t)b * N_ * N_ + (size_t)m0 * N_;
    const short* Bbase = gT   + (size_t)b * C_ * N_ + (size_t)n0 * N_;

    f32x4 acc[4][2];
#pragma unroll
    for (int m = 0; m < 4; ++m)
#pragma unroll
        for (int n = 0; n < 2; ++n) acc[m][n] = (f32x4){0.f, 0.f, 0.f, 0.f};

    for (int k0 = 0; k0 < N_; k0 += 64) {
        // stage A: 16 chunks of 1KB (8 rows each); 4 per wave
#pragma unroll
        for (int q = 0; q < 4; ++q) {
            int chunk = wid * 4 + q;
            int row   = chunk * 8 + lr;
            GL2LDS(Abase + (size_t)row * N_ + k0 + ls * 8, As + chunk * 512);
        }
        // stage B: 8 chunks; 2 per wave
#pragma unroll
        for (int q = 0; q < 2; ++q) {
            int chunk = wid * 2 + q;
            int row   = chunk * 8 + lr;
            GL2LDS(Bbase + (size_t)row * N_ + k0 + ls * 8, Bs + chunk * 512);
        }
        __syncthreads();   // compiler emits vmcnt(0) drain before barrier
#pragma unroll
        for (int kk = 0; kk < 2; ++kk) {
            const int ko = kk * 32 + (lane >> 4) * 8;
            bf16x8 a[4], bb[2];
#pragma unroll
            for (int m = 0; m < 4; ++m) {
                int row = wr * 64 + m * 16 + (lane & 15);
                a[m] = *reinterpret_cast<const bf16x8*>(&As[row * 64 + (ko ^ ((row & 7) * 8))]);
            }
#pragma unroll
            for (int n = 0; n < 2; ++n) {
                int row = wc * 32 + n * 16 + (lane & 15);
                bb[n] = *reinterpret_cast<const bf16x8*>(&Bs[row * 64 + (ko ^ ((row & 7) * 8))]);
            }
#pragma unroll
            for (int m = 0; m < 4; ++m)
#pragma unroll
                for (int n = 0; n < 2; ++n)
                    acc[m][n] = __builtin_amdgcn_mfma_f32_16x16x32_bf16(a[m], bb[n], acc[m][n], 0, 0, 0);
        }
        __syncthreads();
    }
    // epilogue: C/D layout col=lane&15, row=(lane>>4)*4+reg
    float* obase = out + (size_t)b * N_ * C_;
#pragma unroll
    for (int m = 0; m < 4; ++m) {
        int gr = m0 + wr * 64 + m * 16 + (lane >> 4) * 4;
#pragma unroll
        for (int n = 0; n < 2; ++n) {
            int gc = n0 + wc * 32 + n * 16 + (lane & 15);
#pragma unroll
            for (int r = 0; r < 4; ++r)
                obase[(size_t)(gr + r) * C_ + gc] = acc[m][n][r];
        }
    }
}

// ---------------------------------------------------------------------------
// Kernel 7: out /= den
// ---------------------------------------------------------------------------
__global__ __launch_bounds__(256)
void div_kernel(float* __restrict__ out, const float* __restrict__ den) {
    size_t idx = (size_t)blockIdx.x * 256 + threadIdx.x;   // float4 index
    const size_t total4 = (size_t)B_ * N_ * C_ / 4;
    if (idx >= total4) return;
    size_t c0  = idx * 4;
    size_t row = c0 / C_;
    int    col = (int)(c0 % C_);
    float inv = 1.0f / den[row * 8 + (col >> 6)];
    float4 v = reinterpret_cast<float4*>(out)[idx];
    v.x *= inv; v.y *= inv; v.z *= inv; v.w *= inv;
    reinterpret_cast<float4*>(out)[idx] = v;
}

// ---------------------------------------------------------------------------
extern "C" void kernel_launch(void* const* d_in, const int* in_sizes, int n_in,
                              void* d_out, int out_size, void* d_ws, size_t ws_size,
                              hipStream_t stream) {
    const float* x        = (const float*)d_in[0];
    const int*   adj      = (const int*)d_in[1];
    const float* weight   = (const float*)d_in[2];
    // d_in[3] = attn_src : unused (cancels in softmax over neighbors j)
    const float* attn_dst = (const float*)d_in[4];
    float* out = (float*)d_out;

    // workspace layout:
    //   h    : B*N*C fp32   = 16 MiB
    //   eT   : B*H*N fp32   = 256 KiB
    //   den  : B*N*H fp32   = 256 KiB
    //   eTb  : B*H*N bf16   = 128 KiB
    //   adjb : B*N*N bf16   = 32 MiB
    //   gT   : B*C*N bf16   = 8 MiB
    float* h   = (float*)d_ws;
    float* eT  = h + (size_t)B_ * N_ * C_;
    float* den = eT + (size_t)B_ * H_ * N_;
    short* eTb = (short*)(den + (size_t)B_ * N_ * H_);
    short* adjb = eTb + (size_t)B_ * H_ * N_;
    short* gT   = adjb + (size_t)B_ * N_ * N_;

    // 1. projection (fp32)
    {
        dim3 grid((B_ * N_) / 128, C_ / 128);
        proj_gemm<<<grid, 256, 0, stream>>>(x, weight, h);
    }
    // 2. e = exp(h . attn_dst), transposed layouts
    {
        dim3 grid((B_ * N_) / 4);
        e_kernel<<<grid, 256, 0, stream>>>(h, attn_dst, eT, eTb);
    }
    // 3. adj -> bf16
    {
        dim3 grid((unsigned)((size_t)B_ * N_ * N_ / 8 / 256));
        adjb_kernel<<<grid, 256, 0, stream>>>(adj, adjb);
    }
    // 4. gT = bf16(e * h), [b][c][j]
    {
        dim3 grid(N_ / 64, C_ / 64, B_);
        gT_kernel<<<grid, 256, 0, stream>>>(h, eT, gT);
    }
    // 5. denominator
    {
        dim3 grid(B_ * N_);
        den_kernel<<<grid, 256, 0, stream>>>(adjb, eTb, den);
    }
    // 6. numerator GEMM (MFMA) -> out
    {
        dim3 grid(N_ / 128, C_ / 64, B_);
        agg_mfma<<<grid, 256, 0, stream>>>(adjb, gT, out);
    }
    // 7. divide
    {
        size_t total4 = (size_t)B_ * N_ * C_ / 4;
        dim3 grid((unsigned)((total4 + 255) / 256));
        div_kernel<<<grid, 256, 0, stream>>>(out, den);
    }
}

// Round 3
// 93.049 us; speedup vs baseline: 3.6238x; 1.3731x over previous
//
#include <hip/hip_runtime.h>
#include <hip/hip_bf16.h>
#include <math.h>

#define B_    4
#define N_    2048
#define INF_  256
#define OUTF_ 64
#define H_    8
#define C_    512   // H_*OUTF_

typedef __attribute__((ext_vector_type(8))) short  bf16x8;
typedef __attribute__((ext_vector_type(4))) float  f32x4;

static __device__ __forceinline__ short f2b(float f) {
    union { float f; unsigned u; } v; v.f = f;
    unsigned r = (v.u + 0x7FFFu + ((v.u >> 16) & 1u)) >> 16;  // RNE
    return (short)r;
}
static __device__ __forceinline__ float b2f(short s) {
    union { unsigned u; float f; } v; v.u = ((unsigned)(unsigned short)s) << 16;
    return v.f;
}

#define GL2LDS(gsrc, ldst)                                                          \
    __builtin_amdgcn_global_load_lds(                                               \
        (const __attribute__((address_space(1))) void*)(gsrc),                      \
        (__attribute__((address_space(3))) void*)(ldst), 16, 0, 0)

// ---------------------------------------------------------------------------
// Kernel 1: casts. blocks [0,1024): x -> xb (bf16). blocks [1024,1056):
// weight[256][512] -> wbT[512][256] (bf16, transposed) via LDS tiles.
// ---------------------------------------------------------------------------
__global__ __launch_bounds__(256)
void cast_kernel(const float* __restrict__ x, const float* __restrict__ w,
                 short* __restrict__ xb, short* __restrict__ wbT) {
    __shared__ short T[64][72];
    if (blockIdx.x < 1024) {
        size_t i8 = (size_t)blockIdx.x * 256 + threadIdx.x;
        const float4* p = reinterpret_cast<const float4*>(x + i8 * 8);
        float4 v0 = p[0], v1 = p[1];
        bf16x8 o;
        o[0] = f2b(v0.x); o[1] = f2b(v0.y); o[2] = f2b(v0.z); o[3] = f2b(v0.w);
        o[4] = f2b(v1.x); o[5] = f2b(v1.y); o[6] = f2b(v1.z); o[7] = f2b(v1.w);
        *reinterpret_cast<bf16x8*>(xb + i8 * 8) = o;
    } else {
        int blk = blockIdx.x - 1024;          // 32 blocks: 8 c-tiles x 4 k-tiles
        int c0 = (blk & 7) * 64;
        int k0 = (blk >> 3) * 64;
        int t = threadIdx.x;
        int cl = (t & 15) * 4;
#pragma unroll
        for (int p = 0; p < 4; ++p) {
            int kl = p * 16 + (t >> 4);
            float4 v = *reinterpret_cast<const float4*>(&w[(size_t)(k0 + kl) * C_ + c0 + cl]);
            T[cl + 0][kl] = f2b(v.x);
            T[cl + 1][kl] = f2b(v.y);
            T[cl + 2][kl] = f2b(v.z);
            T[cl + 3][kl] = f2b(v.w);
        }
        __syncthreads();
        int cr = t >> 2;
        int ks = (t & 3) * 16;
        short* dst = &wbT[(size_t)(c0 + cr) * INF_ + k0 + ks];
        *reinterpret_cast<bf16x8*>(dst)     = *reinterpret_cast<const bf16x8*>(&T[cr][ks]);
        *reinterpret_cast<bf16x8*>(dst + 8) = *reinterpret_cast<const bf16x8*>(&T[cr][ks + 8]);
    }
}

// ---------------------------------------------------------------------------
// Kernel 2: projection GEMM (bf16 MFMA): hb[8192][512] = xb @ wbT^T
// BM=128, BN=64, BK=64; 4 waves; same staging/swizzle as validated agg_mfma.
// ---------------------------------------------------------------------------
__global__ __launch_bounds__(256)
void proj_mfma(const short* __restrict__ xb, const short* __restrict__ wbT,
               short* __restrict__ hb) {
    __shared__ short As[128 * 64];
    __shared__ short Bs[64 * 64];
    const int m0 = blockIdx.x * 128;
    const int n0 = blockIdx.y * 64;
    const int wid  = threadIdx.x >> 6;
    const int lane = threadIdx.x & 63;
    const int wr = wid >> 1, wc = wid & 1;
    const int lr = lane >> 3;
    const int ls = (lane & 7) ^ lr;
    const short* Abase = xb + (size_t)m0 * INF_;
    const short* Bbase = wbT + (size_t)n0 * INF_;

    f32x4 acc[4][2];
#pragma unroll
    for (int m = 0; m < 4; ++m)
#pragma unroll
        for (int n = 0; n < 2; ++n) acc[m][n] = (f32x4){0.f, 0.f, 0.f, 0.f};

    for (int k0 = 0; k0 < INF_; k0 += 64) {
#pragma unroll
        for (int q = 0; q < 4; ++q) {
            int chunk = wid * 4 + q;
            int row   = chunk * 8 + lr;
            GL2LDS(Abase + (size_t)row * INF_ + k0 + ls * 8, As + chunk * 512);
        }
#pragma unroll
        for (int q = 0; q < 2; ++q) {
            int chunk = wid * 2 + q;
            int row   = chunk * 8 + lr;
            GL2LDS(Bbase + (size_t)row * INF_ + k0 + ls * 8, Bs + chunk * 512);
        }
        __syncthreads();
#pragma unroll
        for (int kk = 0; kk < 2; ++kk) {
            const int ko = kk * 32 + (lane >> 4) * 8;
            bf16x8 a[4], bb[2];
#pragma unroll
            for (int m = 0; m < 4; ++m) {
                int row = wr * 64 + m * 16 + (lane & 15);
                a[m] = *reinterpret_cast<const bf16x8*>(&As[row * 64 + (ko ^ ((row & 7) * 8))]);
            }
#pragma unroll
            for (int n = 0; n < 2; ++n) {
                int row = wc * 32 + n * 16 + (lane & 15);
                bb[n] = *reinterpret_cast<const bf16x8*>(&Bs[row * 64 + (ko ^ ((row & 7) * 8))]);
            }
#pragma unroll
            for (int m = 0; m < 4; ++m)
#pragma unroll
                for (int n = 0; n < 2; ++n)
                    acc[m][n] = __builtin_amdgcn_mfma_f32_16x16x32_bf16(a[m], bb[n], acc[m][n], 0, 0, 0);
        }
        __syncthreads();
    }
#pragma unroll
    for (int m = 0; m < 4; ++m) {
        int gr = m0 + wr * 64 + m * 16 + (lane >> 4) * 4;
#pragma unroll
        for (int n = 0; n < 2; ++n) {
            int gc = n0 + wc * 32 + n * 16 + (lane & 15);
#pragma unroll
            for (int r = 0; r < 4; ++r)
                hb[(size_t)(gr + r) * C_ + gc] = f2b(acc[m][n][r]);
        }
    }
}

// ---------------------------------------------------------------------------
// Kernel 3: e[b,j,h] = exp( sum_f hb[b,j,h*64+f] * attn_dst[h,f] )  (fp32 out)
// one wave per row
// ---------------------------------------------------------------------------
__global__ __launch_bounds__(256)
void e_kernel(const short* __restrict__ hb, const float* __restrict__ attn_dst,
              float* __restrict__ e) {
    int row  = blockIdx.x * 4 + (threadIdx.x >> 6);
    int lane = threadIdx.x & 63;
    const short* hr = hb + (size_t)row * C_;
    bf16x8 hv = *reinterpret_cast<const bf16x8*>(&hr[lane * 8]);
    float4 av0 = *reinterpret_cast<const float4*>(&attn_dst[lane * 8]);
    float4 av1 = *reinterpret_cast<const float4*>(&attn_dst[lane * 8 + 4]);
    float s = b2f(hv[0]) * av0.x + b2f(hv[1]) * av0.y + b2f(hv[2]) * av0.z + b2f(hv[3]) * av0.w
            + b2f(hv[4]) * av1.x + b2f(hv[5]) * av1.y + b2f(hv[6]) * av1.z + b2f(hv[7]) * av1.w;
    s += __shfl_xor(s, 1);
    s += __shfl_xor(s, 2);
    s += __shfl_xor(s, 4);
    if ((lane & 7) == 0) e[(size_t)row * 8 + (lane >> 3)] = expf(s);
}

// ---------------------------------------------------------------------------
// Kernel 4: fused adj->bf16 cast + denominator.
// one block (256 threads) per row (b,i): 8 adj values/thread.
//   adjb[b,i,j] = bf16(adj);  den[b,i,h] = sum_j adj * e[b,j,h]
// ---------------------------------------------------------------------------
__global__ __launch_bounds__(256)
void adjden_kernel(const int* __restrict__ adj, const float* __restrict__ e,
                   short* __restrict__ adjb, float* __restrict__ den) {
    __shared__ float red[4][8];
    const int bi = blockIdx.x;
    const int b  = bi >> 11;
    const int*   arow = adj + (size_t)bi * N_;
    const float* eb   = e + (size_t)b * N_ * 8;
    const int j0 = threadIdx.x * 8;
    const int4 v0 = *reinterpret_cast<const int4*>(&arow[j0]);
    const int4 v1 = *reinterpret_cast<const int4*>(&arow[j0 + 4]);
    int av[8] = { v0.x, v0.y, v0.z, v0.w, v1.x, v1.y, v1.z, v1.w };
    bf16x8 o;
#pragma unroll
    for (int u = 0; u < 8; ++u) o[u] = av[u] ? (short)0x3F80 : (short)0;
    *reinterpret_cast<bf16x8*>(adjb + (size_t)bi * N_ + j0) = o;

    float acc[8] = {};
#pragma unroll
    for (int u = 0; u < 8; ++u) {
        if (av[u]) {
            const float4 e0 = *reinterpret_cast<const float4*>(&eb[(size_t)(j0 + u) * 8]);
            const float4 e1 = *reinterpret_cast<const float4*>(&eb[(size_t)(j0 + u) * 8 + 4]);
            acc[0] += e0.x; acc[1] += e0.y; acc[2] += e0.z; acc[3] += e0.w;
            acc[4] += e1.x; acc[5] += e1.y; acc[6] += e1.z; acc[7] += e1.w;
        }
    }
#pragma unroll
    for (int off = 1; off < 64; off <<= 1)
#pragma unroll
        for (int hh = 0; hh < 8; ++hh) acc[hh] += __shfl_xor(acc[hh], off);
    int lane = threadIdx.x & 63, wv = threadIdx.x >> 6;
    if (lane == 0)
#pragma unroll
        for (int hh = 0; hh < 8; ++hh) red[wv][hh] = acc[hh];
    __syncthreads();
    if (threadIdx.x < 8) {
        float s = red[0][threadIdx.x] + red[1][threadIdx.x]
                + red[2][threadIdx.x] + red[3][threadIdx.x];
        den[(size_t)bi * 8 + threadIdx.x] = s;
    }
}

// ---------------------------------------------------------------------------
// Kernel 5: gT[b][c][j] = bf16(e[b,j,c>>6] * hb[b,j,c])  via LDS transpose
// ---------------------------------------------------------------------------
__global__ __launch_bounds__(256)
void gT_kernel(const short* __restrict__ hb, const float* __restrict__ e,
               short* __restrict__ gT) {
    __shared__ short T[64][72];   // [c][j]
    const int b  = blockIdx.z;
    const int j0 = blockIdx.x * 64;
    const int c0 = blockIdx.y * 64;
    const int head = c0 >> 6;
    const int t = threadIdx.x;
    const int cl = (t & 15) * 4;
#pragma unroll
    for (int p = 0; p < 4; ++p) {
        int jl = p * 16 + (t >> 4);
        float ev = e[((size_t)b * N_ + j0 + jl) * 8 + head];
        const short4 v = *reinterpret_cast<const short4*>(&hb[((size_t)b * N_ + j0 + jl) * C_ + c0 + cl]);
        T[cl + 0][jl] = f2b(b2f(v.x) * ev);
        T[cl + 1][jl] = f2b(b2f(v.y) * ev);
        T[cl + 2][jl] = f2b(b2f(v.z) * ev);
        T[cl + 3][jl] = f2b(b2f(v.w) * ev);
    }
    __syncthreads();
    const int cr = t >> 2;
    const int js = (t & 3) * 16;
    short* dst = &gT[((size_t)b * C_ + c0 + cr) * N_ + j0 + js];
    *reinterpret_cast<bf16x8*>(dst)     = *reinterpret_cast<const bf16x8*>(&T[cr][js]);
    *reinterpret_cast<bf16x8*>(dst + 8) = *reinterpret_cast<const bf16x8*>(&T[cr][js + 8]);
}

// ---------------------------------------------------------------------------
// Kernel 6: numerator GEMM (bf16 MFMA) + fused divide:
//   out[b,i,c] = (sum_j adjb[b,i,j] * gT[b,c,j]) / den[b,i,c>>6]
// BM=128, BN=64, BK=64; head uniform per block (BN=64 aligned).
// ---------------------------------------------------------------------------
__global__ __launch_bounds__(256)
void agg_mfma(const short* __restrict__ adjb, const short* __restrict__ gT,
              const float* __restrict__ den, float* __restrict__ out) {
    __shared__ short As[128 * 64];
    __shared__ short Bs[64 * 64];
    const int b  = blockIdx.z;
    const int m0 = blockIdx.x * 128;
    const int n0 = blockIdx.y * 64;
    const int head = n0 >> 6;
    const int wid  = threadIdx.x >> 6;
    const int lane = threadIdx.x & 63;
    const int wr = wid >> 1, wc = wid & 1;
    const int lr = lane >> 3;
    const int ls = (lane & 7) ^ lr;
    const short* Abase = adjb + (size_t)b * N_ * N_ + (size_t)m0 * N_;
    const short* Bbase = gT   + (size_t)b * C_ * N_ + (size_t)n0 * N_;

    f32x4 acc[4][2];
#pragma unroll
    for (int m = 0; m < 4; ++m)
#pragma unroll
        for (int n = 0; n < 2; ++n) acc[m][n] = (f32x4){0.f, 0.f, 0.f, 0.f};

    for (int k0 = 0; k0 < N_; k0 += 64) {
#pragma unroll
        for (int q = 0; q < 4; ++q) {
            int chunk = wid * 4 + q;
            int row   = chunk * 8 + lr;
            GL2LDS(Abase + (size_t)row * N_ + k0 + ls * 8, As + chunk * 512);
        }
#pragma unroll
        for (int q = 0; q < 2; ++q) {
            int chunk = wid * 2 + q;
            int row   = chunk * 8 + lr;
            GL2LDS(Bbase + (size_t)row * N_ + k0 + ls * 8, Bs + chunk * 512);
        }
        __syncthreads();
#pragma unroll
        for (int kk = 0; kk < 2; ++kk) {
            const int ko = kk * 32 + (lane >> 4) * 8;
            bf16x8 a[4], bb[2];
#pragma unroll
            for (int m = 0; m < 4; ++m) {
                int row = wr * 64 + m * 16 + (lane & 15);
                a[m] = *reinterpret_cast<const bf16x8*>(&As[row * 64 + (ko ^ ((row & 7) * 8))]);
            }
#pragma unroll
            for (int n = 0; n < 2; ++n) {
                int row = wc * 32 + n * 16 + (lane & 15);
                bb[n] = *reinterpret_cast<const bf16x8*>(&Bs[row * 64 + (ko ^ ((row & 7) * 8))]);
            }
#pragma unroll
            for (int m = 0; m < 4; ++m)
#pragma unroll
                for (int n = 0; n < 2; ++n)
                    acc[m][n] = __builtin_amdgcn_mfma_f32_16x16x32_bf16(a[m], bb[n], acc[m][n], 0, 0, 0);
        }
        __syncthreads();
    }
    float* obase = out + (size_t)b * N_ * C_;
    const float* denb = den + (size_t)b * N_ * 8;
#pragma unroll
    for (int m = 0; m < 4; ++m) {
        int gr = m0 + wr * 64 + m * 16 + (lane >> 4) * 4;
        float inv[4];
#pragma unroll
        for (int r = 0; r < 4; ++r) inv[r] = 1.0f / denb[(size_t)(gr + r) * 8 + head];
#pragma unroll
        for (int n = 0; n < 2; ++n) {
            int gc = n0 + wc * 32 + n * 16 + (lane & 15);
#pragma unroll
            for (int r = 0; r < 4; ++r)
                obase[(size_t)(gr + r) * C_ + gc] = acc[m][n][r] * inv[r];
        }
    }
}

// ---------------------------------------------------------------------------
extern "C" void kernel_launch(void* const* d_in, const int* in_sizes, int n_in,
                              void* d_out, int out_size, void* d_ws, size_t ws_size,
                              hipStream_t stream) {
    const float* x        = (const float*)d_in[0];
    const int*   adj      = (const int*)d_in[1];
    const float* weight   = (const float*)d_in[2];
    // d_in[3] = attn_src : unused (cancels in softmax over neighbors j)
    const float* attn_dst = (const float*)d_in[4];
    float* out = (float*)d_out;

    // workspace (bytes):
    //   xb   : 2M bf16  =  4 MiB
    //   wbT  : 128K bf16 = 256 KiB
    //   hb   : 4M bf16  =  8 MiB
    //   e    : 64K f32  = 256 KiB
    //   den  : 64K f32  = 256 KiB
    //   adjb : 16M bf16 = 32 MiB
    //   gT   : 4M bf16  =  8 MiB
    short* xb   = (short*)d_ws;
    short* wbT  = xb + (size_t)B_ * N_ * INF_;
    short* hb   = wbT + (size_t)C_ * INF_;
    float* e    = (float*)(hb + (size_t)B_ * N_ * C_);
    float* den  = e + (size_t)B_ * N_ * H_;
    short* adjb = (short*)(den + (size_t)B_ * N_ * H_);
    short* gT   = adjb + (size_t)B_ * N_ * N_;

    // 1. casts: x->bf16, weight->bf16 transposed
    cast_kernel<<<dim3(1024 + 32), 256, 0, stream>>>(x, weight, xb, wbT);
    // 2. projection (bf16 MFMA)
    proj_mfma<<<dim3((B_ * N_) / 128, C_ / 64), 256, 0, stream>>>(xb, wbT, hb);
    // 3. e = exp(h . attn_dst)
    e_kernel<<<dim3((B_ * N_) / 4), 256, 0, stream>>>(hb, attn_dst, e);
    // 4. fused adj cast + denominator
    adjden_kernel<<<dim3(B_ * N_), 256, 0, stream>>>(adj, e, adjb, den);
    // 5. gT = bf16(e * h), [b][c][j]
    gT_kernel<<<dim3(N_ / 64, C_ / 64, B_), 256, 0, stream>>>(hb, e, gT);
    // 6. numerator GEMM (MFMA) + divide -> out
    agg_mfma<<<dim3(N_ / 128, C_ / 64, B_), 256, 0, stream>>>(adjb, gT, den, out);
}

// Round 4
// 70.737 us; speedup vs baseline: 4.7669x; 1.3154x over previous
//
#include <hip/hip_runtime.h>
#include <hip/hip_bf16.h>
#include <math.h>

#define B_    4
#define N_    2048
#define INF_  256
#define OUTF_ 64
#define H_    8
#define C_    512   // H_*OUTF_

typedef __attribute__((ext_vector_type(8))) short  bf16x8;
typedef __attribute__((ext_vector_type(4))) float  f32x4;

static __device__ __forceinline__ short f2b(float f) {
    union { float f; unsigned u; } v; v.f = f;
    unsigned r = (v.u + 0x7FFFu + ((v.u >> 16) & 1u)) >> 16;  // RNE
    return (short)r;
}
static __device__ __forceinline__ float b2f(short s) {
    union { unsigned u; float f; } v; v.u = ((unsigned)(unsigned short)s) << 16;
    return v.f;
}

#define GL2LDS(gsrc, ldst)                                                          \
    __builtin_amdgcn_global_load_lds(                                               \
        (const __attribute__((address_space(1))) void*)(gsrc),                      \
        (__attribute__((address_space(3))) void*)(ldst), 16, 0, 0)

// ---------------------------------------------------------------------------
// Kernel 1: casts. blocks [0,1024): x -> xb (bf16). blocks [1024,1056):
// weight[256][512] -> wbT[512][256] (bf16, transposed) via LDS tiles.
// ---------------------------------------------------------------------------
__global__ __launch_bounds__(256)
void cast_kernel(const float* __restrict__ x, const float* __restrict__ w,
                 short* __restrict__ xb, short* __restrict__ wbT) {
    __shared__ short T[64][72];
    if (blockIdx.x < 1024) {
        size_t i8 = (size_t)blockIdx.x * 256 + threadIdx.x;
        const float4* p = reinterpret_cast<const float4*>(x + i8 * 8);
        float4 v0 = p[0], v1 = p[1];
        bf16x8 o;
        o[0] = f2b(v0.x); o[1] = f2b(v0.y); o[2] = f2b(v0.z); o[3] = f2b(v0.w);
        o[4] = f2b(v1.x); o[5] = f2b(v1.y); o[6] = f2b(v1.z); o[7] = f2b(v1.w);
        *reinterpret_cast<bf16x8*>(xb + i8 * 8) = o;
    } else {
        int blk = blockIdx.x - 1024;          // 32 blocks: 8 c-tiles x 4 k-tiles
        int c0 = (blk & 7) * 64;
        int k0 = (blk >> 3) * 64;
        int t = threadIdx.x;
        int cl = (t & 15) * 4;
#pragma unroll
        for (int p = 0; p < 4; ++p) {
            int kl = p * 16 + (t >> 4);
            float4 v = *reinterpret_cast<const float4*>(&w[(size_t)(k0 + kl) * C_ + c0 + cl]);
            T[cl + 0][kl] = f2b(v.x);
            T[cl + 1][kl] = f2b(v.y);
            T[cl + 2][kl] = f2b(v.z);
            T[cl + 3][kl] = f2b(v.w);
        }
        __syncthreads();
        int cr = t >> 2;
        int ks = (t & 3) * 16;
        short* dst = &wbT[(size_t)(c0 + cr) * INF_ + k0 + ks];
        *reinterpret_cast<bf16x8*>(dst)     = *reinterpret_cast<const bf16x8*>(&T[cr][ks]);
        *reinterpret_cast<bf16x8*>(dst + 8) = *reinterpret_cast<const bf16x8*>(&T[cr][ks + 8]);
    }
}

// ---------------------------------------------------------------------------
// Kernel 2: adjb = bf16(adj)  (pure streaming cast, 8 per thread)
// ---------------------------------------------------------------------------
__global__ __launch_bounds__(256)
void adjb_kernel(const int* __restrict__ adj, short* __restrict__ adjb) {
    size_t i8 = (size_t)blockIdx.x * 256 + threadIdx.x;
    const int4* p = reinterpret_cast<const int4*>(adj + i8 * 8);
    int4 v0 = p[0], v1 = p[1];
    bf16x8 o;
    o[0] = v0.x ? (short)0x3F80 : (short)0;
    o[1] = v0.y ? (short)0x3F80 : (short)0;
    o[2] = v0.z ? (short)0x3F80 : (short)0;
    o[3] = v0.w ? (short)0x3F80 : (short)0;
    o[4] = v1.x ? (short)0x3F80 : (short)0;
    o[5] = v1.y ? (short)0x3F80 : (short)0;
    o[6] = v1.z ? (short)0x3F80 : (short)0;
    o[7] = v1.w ? (short)0x3F80 : (short)0;
    *reinterpret_cast<bf16x8*>(adjb + i8 * 8) = o;
}

// ---------------------------------------------------------------------------
// Kernel 3: projection GEMM (bf16 MFMA): hb[8192][512] = xb @ wbT^T
// ---------------------------------------------------------------------------
__global__ __launch_bounds__(256)
void proj_mfma(const short* __restrict__ xb, const short* __restrict__ wbT,
               short* __restrict__ hb) {
    __shared__ short As[128 * 64];
    __shared__ short Bs[64 * 64];
    const int m0 = blockIdx.x * 128;
    const int n0 = blockIdx.y * 64;
    const int wid  = threadIdx.x >> 6;
    const int lane = threadIdx.x & 63;
    const int wr = wid >> 1, wc = wid & 1;
    const int lr = lane >> 3;
    const int ls = (lane & 7) ^ lr;
    const short* Abase = xb + (size_t)m0 * INF_;
    const short* Bbase = wbT + (size_t)n0 * INF_;

    f32x4 acc[4][2];
#pragma unroll
    for (int m = 0; m < 4; ++m)
#pragma unroll
        for (int n = 0; n < 2; ++n) acc[m][n] = (f32x4){0.f, 0.f, 0.f, 0.f};

    for (int k0 = 0; k0 < INF_; k0 += 64) {
#pragma unroll
        for (int q = 0; q < 4; ++q) {
            int chunk = wid * 4 + q;
            int row   = chunk * 8 + lr;
            GL2LDS(Abase + (size_t)row * INF_ + k0 + ls * 8, As + chunk * 512);
        }
#pragma unroll
        for (int q = 0; q < 2; ++q) {
            int chunk = wid * 2 + q;
            int row   = chunk * 8 + lr;
            GL2LDS(Bbase + (size_t)row * INF_ + k0 + ls * 8, Bs + chunk * 512);
        }
        __syncthreads();
#pragma unroll
        for (int kk = 0; kk < 2; ++kk) {
            const int ko = kk * 32 + (lane >> 4) * 8;
            bf16x8 a[4], bb[2];
#pragma unroll
            for (int m = 0; m < 4; ++m) {
                int row = wr * 64 + m * 16 + (lane & 15);
                a[m] = *reinterpret_cast<const bf16x8*>(&As[row * 64 + (ko ^ ((row & 7) * 8))]);
            }
#pragma unroll
            for (int n = 0; n < 2; ++n) {
                int row = wc * 32 + n * 16 + (lane & 15);
                bb[n] = *reinterpret_cast<const bf16x8*>(&Bs[row * 64 + (ko ^ ((row & 7) * 8))]);
            }
#pragma unroll
            for (int m = 0; m < 4; ++m)
#pragma unroll
                for (int n = 0; n < 2; ++n)
                    acc[m][n] = __builtin_amdgcn_mfma_f32_16x16x32_bf16(a[m], bb[n], acc[m][n], 0, 0, 0);
        }
        __syncthreads();
    }
#pragma unroll
    for (int m = 0; m < 4; ++m) {
        int gr = m0 + wr * 64 + m * 16 + (lane >> 4) * 4;
#pragma unroll
        for (int n = 0; n < 2; ++n) {
            int gc = n0 + wc * 32 + n * 16 + (lane & 15);
#pragma unroll
            for (int r = 0; r < 4; ++r)
                hb[(size_t)(gr + r) * C_ + gc] = f2b(acc[m][n][r]);
        }
    }
}

// ---------------------------------------------------------------------------
// Kernel 4: ebT[b][h][j] = bf16(exp( sum_f hb[b,j,h*64+f] * attn_dst[h,f] ))
// one wave per row
// ---------------------------------------------------------------------------
__global__ __launch_bounds__(256)
void e_kernel(const short* __restrict__ hb, const float* __restrict__ attn_dst,
              short* __restrict__ ebT) {
    int row  = blockIdx.x * 4 + (threadIdx.x >> 6);
    int lane = threadIdx.x & 63;
    const short* hr = hb + (size_t)row * C_;
    bf16x8 hv = *reinterpret_cast<const bf16x8*>(&hr[lane * 8]);
    float4 av0 = *reinterpret_cast<const float4*>(&attn_dst[lane * 8]);
    float4 av1 = *reinterpret_cast<const float4*>(&attn_dst[lane * 8 + 4]);
    float s = b2f(hv[0]) * av0.x + b2f(hv[1]) * av0.y + b2f(hv[2]) * av0.z + b2f(hv[3]) * av0.w
            + b2f(hv[4]) * av1.x + b2f(hv[5]) * av1.y + b2f(hv[6]) * av1.z + b2f(hv[7]) * av1.w;
    s += __shfl_xor(s, 1);
    s += __shfl_xor(s, 2);
    s += __shfl_xor(s, 4);
    if ((lane & 7) == 0) {
        int b = row >> 11, j = row & (N_ - 1), hh = lane >> 3;
        ebT[((size_t)b * H_ + hh) * N_ + j] = f2b(expf(s));
    }
}

// ---------------------------------------------------------------------------
// Kernel 5: gT[b][c][j] = bf16(e_bf16[b,c>>6,j] * hb[b,j,c])  via LDS transpose
// ---------------------------------------------------------------------------
__global__ __launch_bounds__(256)
void gT_kernel(const short* __restrict__ hb, const short* __restrict__ ebT,
               short* __restrict__ gT) {
    __shared__ short T[64][72];   // [c][j]
    const int b  = blockIdx.z;
    const int j0 = blockIdx.x * 64;
    const int c0 = blockIdx.y * 64;
    const int head = c0 >> 6;
    const int t = threadIdx.x;
    const int cl = (t & 15) * 4;
#pragma unroll
    for (int p = 0; p < 4; ++p) {
        int jl = p * 16 + (t >> 4);
        float ev = b2f(ebT[((size_t)b * H_ + head) * N_ + j0 + jl]);
        const short4 v = *reinterpret_cast<const short4*>(&hb[((size_t)b * N_ + j0 + jl) * C_ + c0 + cl]);
        T[cl + 0][jl] = f2b(b2f(v.x) * ev);
        T[cl + 1][jl] = f2b(b2f(v.y) * ev);
        T[cl + 2][jl] = f2b(b2f(v.z) * ev);
        T[cl + 3][jl] = f2b(b2f(v.w) * ev);
    }
    __syncthreads();
    const int cr = t >> 2;
    const int js = (t & 3) * 16;
    short* dst = &gT[((size_t)b * C_ + c0 + cr) * N_ + j0 + js];
    *reinterpret_cast<bf16x8*>(dst)     = *reinterpret_cast<const bf16x8*>(&T[cr][js]);
    *reinterpret_cast<bf16x8*>(dst + 8) = *reinterpret_cast<const bf16x8*>(&T[cr][js + 8]);
}

// ---------------------------------------------------------------------------
// Kernel 6: numerator GEMM (bf16 MFMA) + in-kernel denominator + divide:
//   num[i,c] = sum_j adjb[b,i,j] * gT[b,c,j]
//   den[i]   = sum_j adjb[b,i,j] * e[b,head,j]   (extra MFMA: every B-col = e)
//   out      = num / den
// BM=128, BN=64, BK=64; head uniform per block.
// ---------------------------------------------------------------------------
__global__ __launch_bounds__(256)
void agg_mfma(const short* __restrict__ adjb, const short* __restrict__ gT,
              const short* __restrict__ ebT, float* __restrict__ out) {
    __shared__ short As[128 * 64];   // 16 KiB
    __shared__ short Bs[64 * 64];    //  8 KiB
    __shared__ short Es[N_];         //  4 KiB : e[b, head, 0..2047]
    const int b  = blockIdx.z;
    const int m0 = blockIdx.x * 128;
    const int n0 = blockIdx.y * 64;
    const int head = n0 >> 6;
    const int wid  = threadIdx.x >> 6;
    const int lane = threadIdx.x & 63;
    const int wr = wid >> 1, wc = wid & 1;
    const int lr = lane >> 3;
    const int ls = (lane & 7) ^ lr;
    const short* Abase = adjb + (size_t)b * N_ * N_ + (size_t)m0 * N_;
    const short* Bbase = gT   + (size_t)b * C_ * N_ + (size_t)n0 * N_;
    const short* Ebase = ebT  + ((size_t)b * H_ + head) * N_;

    // preload full e row (4 KiB): each wave stages 1 KiB (64 lanes x 16 B)
    GL2LDS(Ebase + wid * 512 + lane * 8, Es + wid * 512);

    f32x4 acc[4][2];
    f32x4 accd[4];
#pragma unroll
    for (int m = 0; m < 4; ++m) {
        accd[m] = (f32x4){0.f, 0.f, 0.f, 0.f};
#pragma unroll
        for (int n = 0; n < 2; ++n) acc[m][n] = (f32x4){0.f, 0.f, 0.f, 0.f};
    }

    for (int k0 = 0; k0 < N_; k0 += 64) {
#pragma unroll
        for (int q = 0; q < 4; ++q) {
            int chunk = wid * 4 + q;
            int row   = chunk * 8 + lr;
            GL2LDS(Abase + (size_t)row * N_ + k0 + ls * 8, As + chunk * 512);
        }
#pragma unroll
        for (int q = 0; q < 2; ++q) {
            int chunk = wid * 2 + q;
            int row   = chunk * 8 + lr;
            GL2LDS(Bbase + (size_t)row * N_ + k0 + ls * 8, Bs + chunk * 512);
        }
        __syncthreads();
#pragma unroll
        for (int kk = 0; kk < 2; ++kk) {
            const int ko = kk * 32 + (lane >> 4) * 8;
            bf16x8 a[4], bb[2], be;
#pragma unroll
            for (int m = 0; m < 4; ++m) {
                int row = wr * 64 + m * 16 + (lane & 15);
                a[m] = *reinterpret_cast<const bf16x8*>(&As[row * 64 + (ko ^ ((row & 7) * 8))]);
            }
#pragma unroll
            for (int n = 0; n < 2; ++n) {
                int row = wc * 32 + n * 16 + (lane & 15);
                bb[n] = *reinterpret_cast<const bf16x8*>(&Bs[row * 64 + (ko ^ ((row & 7) * 8))]);
            }
            be = *reinterpret_cast<const bf16x8*>(&Es[k0 + ko]);   // same for all cols
#pragma unroll
            for (int m = 0; m < 4; ++m) {
#pragma unroll
                for (int n = 0; n < 2; ++n)
                    acc[m][n] = __builtin_amdgcn_mfma_f32_16x16x32_bf16(a[m], bb[n], acc[m][n], 0, 0, 0);
                accd[m] = __builtin_amdgcn_mfma_f32_16x16x32_bf16(a[m], be, accd[m], 0, 0, 0);
            }
        }
        __syncthreads();
    }
    // epilogue: every lane's accd[m][r] = den for row gr+r (all B-cols equal)
    float* obase = out + (size_t)b * N_ * C_;
#pragma unroll
    for (int m = 0; m < 4; ++m) {
        int gr = m0 + wr * 64 + m * 16 + (lane >> 4) * 4;
        float inv[4];
#pragma unroll
        for (int r = 0; r < 4; ++r) inv[r] = 1.0f / accd[m][r];
#pragma unroll
        for (int n = 0; n < 2; ++n) {
            int gc = n0 + wc * 32 + n * 16 + (lane & 15);
#pragma unroll
            for (int r = 0; r < 4; ++r)
                obase[(size_t)(gr + r) * C_ + gc] = acc[m][n][r] * inv[r];
        }
    }
}

// ---------------------------------------------------------------------------
extern "C" void kernel_launch(void* const* d_in, const int* in_sizes, int n_in,
                              void* d_out, int out_size, void* d_ws, size_t ws_size,
                              hipStream_t stream) {
    const float* x        = (const float*)d_in[0];
    const int*   adj      = (const int*)d_in[1];
    const float* weight   = (const float*)d_in[2];
    // d_in[3] = attn_src : unused (cancels in softmax over neighbors j)
    const float* attn_dst = (const float*)d_in[4];
    float* out = (float*)d_out;

    // workspace:
    //   xb   : 4 MiB bf16
    //   wbT  : 256 KiB bf16
    //   hb   : 8 MiB bf16
    //   ebT  : 128 KiB bf16   [b][h][j]
    //   adjb : 32 MiB bf16
    //   gT   : 8 MiB bf16     [b][c][j]
    short* xb   = (short*)d_ws;
    short* wbT  = xb + (size_t)B_ * N_ * INF_;
    short* hb   = wbT + (size_t)C_ * INF_;
    short* ebT  = hb + (size_t)B_ * N_ * C_;
    short* adjb = ebT + (size_t)B_ * H_ * N_;
    short* gT   = adjb + (size_t)B_ * N_ * N_;

    // 1. casts: x->bf16, weight->bf16 transposed
    cast_kernel<<<dim3(1024 + 32), 256, 0, stream>>>(x, weight, xb, wbT);
    // 2. adj -> bf16 (streaming)
    adjb_kernel<<<dim3((unsigned)((size_t)B_ * N_ * N_ / 8 / 256)), 256, 0, stream>>>(adj, adjb);
    // 3. projection (bf16 MFMA)
    proj_mfma<<<dim3((B_ * N_) / 128, C_ / 64), 256, 0, stream>>>(xb, wbT, hb);
    // 4. e = bf16(exp(h . attn_dst)), transposed [b][h][j]
    e_kernel<<<dim3((B_ * N_) / 4), 256, 0, stream>>>(hb, attn_dst, ebT);
    // 5. gT = bf16(e * h), [b][c][j]
    gT_kernel<<<dim3(N_ / 64, C_ / 64, B_), 256, 0, stream>>>(hb, ebT, gT);
    // 6. numerator GEMM + denominator (MFMA) + divide -> out
    agg_mfma<<<dim3(N_ / 128, C_ / 64, B_), 256, 0, stream>>>(adjb, gT, ebT, out);
}